// Round 1
// baseline (2031.842 us; speedup 1.0000x reference)
//
#include <hip/hip_runtime.h>
#include <hip/hip_bf16.h>

// Problem constants (fixed by the reference)
#define B_ 1024
#define L_ 32
#define M_ 128
#define N_ 4096
#define S_ 32
#define ROWS (B_ * L_)          // 32768 rows of length N_

// ---------------------------------------------------------------------------
// K0: transpose W_d [L][M][N] -> W_dT [L][N][M] (for coalesced decoder gathers)
// ---------------------------------------------------------------------------
__global__ __launch_bounds__(256) void transpose_wd(const float* __restrict__ Wd,
                                                    float* __restrict__ WdT) {
    __shared__ float t[32][33];
    int l = blockIdx.z;
    int n0 = blockIdx.x * 32, m0 = blockIdx.y * 32;
    int tx = threadIdx.x & 31, ty = threadIdx.x >> 5;   // 8 rows of 32
    const float* src = Wd + (size_t)l * M_ * N_;
    for (int i = ty; i < 32; i += 8)
        t[i][tx] = src[(size_t)(m0 + i) * N_ + n0 + tx];
    __syncthreads();
    float* dst = WdT + (size_t)l * N_ * M_;
    for (int i = ty; i < 32; i += 8)
        dst[(size_t)(n0 + i) * M_ + m0 + tx] = t[tx][i];
}

// ---------------------------------------------------------------------------
// K1: encoder GEMM (f32).  Per layer l: Y = (K_l - b_d[l]) (1024x128) * W_e[l]^T (128x4096)
// Tile 64x64, full K=128 in LDS, 4x4 microtile with float4 LDS reads.
// Writes DENSE y into the y region of d_out.
// ---------------------------------------------------------------------------
#define BM 64
#define BN 64
#define APITCH 132   // 128 + 4 pad (keeps float4 alignment, breaks bank stride)

__global__ __launch_bounds__(256) void encoder_gemm(const float* __restrict__ kin,
                                                    const float* __restrict__ We,
                                                    const float* __restrict__ bd,
                                                    float* __restrict__ y_out) {
    int l   = blockIdx.z;
    int bn0 = blockIdx.x * BN;
    int bm0 = blockIdx.y * BM;
    __shared__ float As[BM][APITCH];
    __shared__ float Bs[BN][APITCH];
    int tid = threadIdx.x;

    const float* bdl = bd + l * M_;
    // load A tile: 64 rows x 128 K = 2048 float4, 8 per thread (coalesced)
    for (int it = 0; it < 8; ++it) {
        int f4 = it * 256 + tid;
        int r  = f4 >> 5;             // /32 float4 per row
        int kv = (f4 & 31) << 2;
        int b  = bm0 + r;
        float4 v  = *reinterpret_cast<const float4*>(kin + ((size_t)(b * L_ + l)) * M_ + kv);
        float4 bb = *reinterpret_cast<const float4*>(bdl + kv);
        v.x -= bb.x; v.y -= bb.y; v.z -= bb.z; v.w -= bb.w;
        *reinterpret_cast<float4*>(&As[r][kv]) = v;
    }
    // load B tile: W_e[l][bn0+r][kv]
    const float* wel = We + (size_t)l * N_ * M_;
    for (int it = 0; it < 8; ++it) {
        int f4 = it * 256 + tid;
        int r  = f4 >> 5;
        int kv = (f4 & 31) << 2;
        float4 v = *reinterpret_cast<const float4*>(wel + (size_t)(bn0 + r) * M_ + kv);
        *reinterpret_cast<float4*>(&Bs[r][kv]) = v;
    }
    __syncthreads();

    int tx = tid & 15, ty = tid >> 4;
    float acc[4][4] = {};
    for (int kk = 0; kk < 128; kk += 4) {
        float4 a[4], bfr[4];
        #pragma unroll
        for (int i = 0; i < 4; ++i) a[i]   = *reinterpret_cast<const float4*>(&As[ty * 4 + i][kk]);
        #pragma unroll
        for (int j = 0; j < 4; ++j) bfr[j] = *reinterpret_cast<const float4*>(&Bs[tx * 4 + j][kk]);
        #pragma unroll
        for (int i = 0; i < 4; ++i)
            #pragma unroll
            for (int j = 0; j < 4; ++j) {
                acc[i][j] = fmaf(a[i].x, bfr[j].x, acc[i][j]);
                acc[i][j] = fmaf(a[i].y, bfr[j].y, acc[i][j]);
                acc[i][j] = fmaf(a[i].z, bfr[j].z, acc[i][j]);
                acc[i][j] = fmaf(a[i].w, bfr[j].w, acc[i][j]);
            }
    }
    // write dense y (scalar stores: y region is only 4B-aligned in d_out)
    for (int i = 0; i < 4; ++i) {
        int b = bm0 + ty * 4 + i;
        float* dst = y_out + ((size_t)(b * L_ + l)) * N_ + bn0 + tx * 4;
        #pragma unroll
        for (int j = 0; j < 4; ++j) dst[j] = acc[i][j];
    }
}

// ---------------------------------------------------------------------------
// K2: exact top-32 per row via MSB-first radix select on |y| bit keys.
// Ties broken by lowest index (matches jax.lax.top_k stability).
// Masks y in place; writes compact (idx, val) lists to ws.
// ---------------------------------------------------------------------------
__device__ __forceinline__ unsigned fkey(float v) {
    return __float_as_uint(fabsf(v));
}

__global__ __launch_bounds__(256) void topk_kernel(float* __restrict__ y,
                                                   int* __restrict__ cidx,
                                                   float* __restrict__ cval) {
    int row = blockIdx.x;                 // row = b*L + l
    float* yr = y + (size_t)row * N_;
    __shared__ float vals[N_];
    __shared__ unsigned hist[256];
    __shared__ unsigned scan[256];
    __shared__ unsigned sh_stat[2];
    int tid = threadIdx.x;

    for (int i = tid; i < N_; i += 256) vals[i] = yr[i];
    __syncthreads();

    unsigned prefix = 0;
    int want = S_;
    for (int shift = 24; shift >= 0; shift -= 8) {
        hist[tid] = 0;
        __syncthreads();
        for (int i = tid; i < N_; i += 256) {
            unsigned kk = fkey(vals[i]);
            if (shift == 24 || (kk >> (shift + 8)) == prefix)
                atomicAdd(&hist[(kk >> shift) & 255], 1u);
        }
        __syncthreads();
        if (tid == 0) {
            unsigned c = 0;
            int d = 255;
            for (; d >= 0; --d) { c += hist[d]; if ((int)c >= want) break; }
            sh_stat[0] = (prefix << 8) | (unsigned)d;
            sh_stat[1] = (unsigned)(want - (int)(c - hist[d]));
        }
        __syncthreads();
        prefix = sh_stat[0];
        want   = (int)sh_stat[1];
        __syncthreads();
    }
    const unsigned T = prefix;    // full 32-bit threshold key
    const int k_rem = want;       // how many key==T to keep (lowest indices)

    // thread t owns contiguous chunk [t*16, t*16+16) for index-ordered scans
    int base = tid * 16;
    int eqc = 0;
    #pragma unroll
    for (int i = 0; i < 16; ++i) eqc += (fkey(vals[base + i]) == T);
    // inclusive Hillis-Steele scan (deterministic)
    scan[tid] = (unsigned)eqc;
    __syncthreads();
    for (int off = 1; off < 256; off <<= 1) {
        unsigned a = scan[tid];
        unsigned b = (tid >= off) ? scan[tid - off] : 0u;
        __syncthreads();
        scan[tid] = a + b;
        __syncthreads();
    }
    int eq_before = (int)scan[tid] - eqc;

    // keep flags with exact tie ranks
    unsigned flags = 0;
    int myeq = 0, keepc = 0;
    #pragma unroll
    for (int i = 0; i < 16; ++i) {
        unsigned kk = fkey(vals[base + i]);
        bool keep = (kk > T) || (kk == T && (eq_before + myeq) < k_rem);
        myeq += (kk == T);
        if (keep) { flags |= (1u << i); ++keepc; }
    }
    scan[tid] = (unsigned)keepc;
    __syncthreads();
    for (int off = 1; off < 256; off <<= 1) {
        unsigned a = scan[tid];
        unsigned b = (tid >= off) ? scan[tid - off] : 0u;
        __syncthreads();
        scan[tid] = a + b;
        __syncthreads();
    }
    int pos = (int)scan[tid] - keepc;   // exclusive

    for (int i = 0; i < 16; ++i) {
        bool keep = (flags >> i) & 1u;
        float v = vals[base + i];
        yr[base + i] = keep ? v : 0.0f;
        if (keep) {
            cidx[(size_t)row * S_ + pos] = base + i;
            cval[(size_t)row * S_ + pos] = v;
            ++pos;
        }
    }
}

// ---------------------------------------------------------------------------
// K3: sparse decoder + per-row squared-residual partial
// k_hat[row][m] = sum_j val_j * WdT[l][idx_j][m]
// ---------------------------------------------------------------------------
__global__ __launch_bounds__(128) void decoder_kernel(const float* __restrict__ WdT,
                                                      const int* __restrict__ cidx,
                                                      const float* __restrict__ cval,
                                                      const float* __restrict__ kin,
                                                      float* __restrict__ khat,
                                                      float* __restrict__ partial) {
    int row = blockIdx.x;
    int l = row & (L_ - 1);
    int m = threadIdx.x;
    __shared__ int   sidx[S_];
    __shared__ float sval[S_];
    __shared__ float red[128];
    if (m < S_) { sidx[m] = cidx[(size_t)row * S_ + m]; sval[m] = cval[(size_t)row * S_ + m]; }
    __syncthreads();
    const float* wt = WdT + (size_t)l * N_ * M_;
    float acc = 0.0f;
    #pragma unroll
    for (int j = 0; j < S_; ++j)
        acc = fmaf(sval[j], wt[(size_t)sidx[j] * M_ + m], acc);
    khat[(size_t)row * M_ + m] = acc;
    float r = acc - kin[(size_t)row * M_ + m];
    red[m] = r * r;
    __syncthreads();
    for (int off = 64; off > 0; off >>= 1) {
        if (m < off) red[m] += red[m + off];
        __syncthreads();
    }
    if (m == 0) partial[row] = red[0];
}

// ---------------------------------------------------------------------------
// K4: deterministic reduction of 32768 partials -> loss
// ---------------------------------------------------------------------------
__global__ __launch_bounds__(256) void reduce_loss(const float* __restrict__ partial,
                                                   float* __restrict__ out_loss) {
    __shared__ float red[256];
    int tid = threadIdx.x;
    float s = 0.0f;
    for (int i = tid; i < ROWS; i += 256) s += partial[i];
    red[tid] = s;
    __syncthreads();
    for (int off = 128; off > 0; off >>= 1) {
        if (tid < off) red[tid] += red[tid + off];
        __syncthreads();
    }
    if (tid == 0) out_loss[0] = red[0] / (float)((size_t)B_ * L_ * M_);
}

// ---------------------------------------------------------------------------
extern "C" void kernel_launch(void* const* d_in, const int* in_sizes, int n_in,
                              void* d_out, int out_size, void* d_ws, size_t ws_size,
                              hipStream_t stream) {
    const float* kin = (const float*)d_in[0];   // [B][L][M]
    const float* We  = (const float*)d_in[1];   // [L][N][M]
    // d_in[2] = b_e (unused by reference encode())
    const float* Wd  = (const float*)d_in[3];   // [L][M][N]
    const float* bd  = (const float*)d_in[4];   // [L][M]
    // d_in[5] = s (==32, hardcoded)

    float* out   = (float*)d_out;
    float* loss  = out;                                   // [1]
    float* khat  = out + 1;                               // [B*L*M]
    float* y_out = out + 1 + (size_t)B_ * L_ * M_;        // [B*L*N]

    // workspace layout (floats)
    float* ws      = (float*)d_ws;
    float* WdT     = ws;                                  // L*N*M      = 16,777,216 f (64 MiB)
    int*   cidx    = (int*)(ws + (size_t)L_ * N_ * M_);   // ROWS*S     =  1,048,576 i
    float* cval    = (float*)(cidx + (size_t)ROWS * S_);  // ROWS*S     =  1,048,576 f
    float* partial = cval + (size_t)ROWS * S_;            // ROWS       =     32,768 f

    // K0: transpose W_d
    transpose_wd<<<dim3(N_ / 32, M_ / 32, L_), 256, 0, stream>>>(Wd, WdT);
    // K1: encoder GEMM -> dense y in d_out
    encoder_gemm<<<dim3(N_ / BN, B_ / BM, L_), 256, 0, stream>>>(kin, We, bd, y_out);
    // K2: top-32 select, mask y in place, emit compact lists
    topk_kernel<<<ROWS, 256, 0, stream>>>(y_out, cidx, cval);
    // K3: sparse decode + residual partials
    decoder_kernel<<<ROWS, 128, 0, stream>>>(WdT, cidx, cval, kin, khat, partial);
    // K4: loss
    reduce_loss<<<1, 256, 0, stream>>>(partial, loss);
}

// Round 2
// 1070.042 us; speedup vs baseline: 1.8988x; 1.8988x over previous
//
#include <hip/hip_runtime.h>
#include <hip/hip_bf16.h>

// Problem constants (fixed by the reference)
#define B_ 1024
#define L_ 32
#define M_ 128
#define N_ 4096
#define S_ 32
#define ROWS (B_ * L_)          // 32768 rows of length N_

// ---------------------------------------------------------------------------
// K0: transpose W_d [L][M][N] -> W_dT [L][N][M] (for coalesced decoder gathers)
// ---------------------------------------------------------------------------
__global__ __launch_bounds__(256) void transpose_wd(const float* __restrict__ Wd,
                                                    float* __restrict__ WdT) {
    __shared__ float t[32][33];
    int l = blockIdx.z;
    int n0 = blockIdx.x * 32, m0 = blockIdx.y * 32;
    int tx = threadIdx.x & 31, ty = threadIdx.x >> 5;   // 8 rows of 32
    const float* src = Wd + (size_t)l * M_ * N_;
    for (int i = ty; i < 32; i += 8)
        t[i][tx] = src[(size_t)(m0 + i) * N_ + n0 + tx];
    __syncthreads();
    float* dst = WdT + (size_t)l * N_ * M_;
    for (int i = ty; i < 32; i += 8)
        dst[(size_t)(n0 + i) * M_ + m0 + tx] = t[tx][i];
}

// ---------------------------------------------------------------------------
// K1: encoder GEMM (f32).  Per layer l: Y = (K_l - b_d[l]) (1024x128) * W_e[l]^T (128x4096)
// ---------------------------------------------------------------------------
#define BM 64
#define BN 64
#define APITCH 132   // 128 + 4 pad

__global__ __launch_bounds__(256) void encoder_gemm(const float* __restrict__ kin,
                                                    const float* __restrict__ We,
                                                    const float* __restrict__ bd,
                                                    float* __restrict__ y_out) {
    int l   = blockIdx.z;
    int bn0 = blockIdx.x * BN;
    int bm0 = blockIdx.y * BM;
    __shared__ float As[BM][APITCH];
    __shared__ float Bs[BN][APITCH];
    int tid = threadIdx.x;

    const float* bdl = bd + l * M_;
    for (int it = 0; it < 8; ++it) {
        int f4 = it * 256 + tid;
        int r  = f4 >> 5;
        int kv = (f4 & 31) << 2;
        int b  = bm0 + r;
        float4 v  = *reinterpret_cast<const float4*>(kin + ((size_t)(b * L_ + l)) * M_ + kv);
        float4 bb = *reinterpret_cast<const float4*>(bdl + kv);
        v.x -= bb.x; v.y -= bb.y; v.z -= bb.z; v.w -= bb.w;
        *reinterpret_cast<float4*>(&As[r][kv]) = v;
    }
    const float* wel = We + (size_t)l * N_ * M_;
    for (int it = 0; it < 8; ++it) {
        int f4 = it * 256 + tid;
        int r  = f4 >> 5;
        int kv = (f4 & 31) << 2;
        float4 v = *reinterpret_cast<const float4*>(wel + (size_t)(bn0 + r) * M_ + kv);
        *reinterpret_cast<float4*>(&Bs[r][kv]) = v;
    }
    __syncthreads();

    int tx = tid & 15, ty = tid >> 4;
    float acc[4][4] = {};
    for (int kk = 0; kk < 128; kk += 4) {
        float4 a[4], bfr[4];
        #pragma unroll
        for (int i = 0; i < 4; ++i) a[i]   = *reinterpret_cast<const float4*>(&As[ty * 4 + i][kk]);
        #pragma unroll
        for (int j = 0; j < 4; ++j) bfr[j] = *reinterpret_cast<const float4*>(&Bs[tx * 4 + j][kk]);
        #pragma unroll
        for (int i = 0; i < 4; ++i)
            #pragma unroll
            for (int j = 0; j < 4; ++j) {
                acc[i][j] = fmaf(a[i].x, bfr[j].x, acc[i][j]);
                acc[i][j] = fmaf(a[i].y, bfr[j].y, acc[i][j]);
                acc[i][j] = fmaf(a[i].z, bfr[j].z, acc[i][j]);
                acc[i][j] = fmaf(a[i].w, bfr[j].w, acc[i][j]);
            }
    }
    for (int i = 0; i < 4; ++i) {
        int b = bm0 + ty * 4 + i;
        float* dst = y_out + ((size_t)(b * L_ + l)) * N_ + bn0 + tx * 4;
        #pragma unroll
        for (int j = 0; j < 4; ++j) dst[j] = acc[i][j];
    }
}

// ---------------------------------------------------------------------------
// K2 (NEW): exact top-32 per row, register-resident.
//   - 16 values/thread in VGPRs (float4 coalesced loads)
//   - block max via shfl_xor + tiny LDS
//   - bisection on a real threshold until candidate count <= POOL
//   - exact all-pairs rank over <= POOL candidates, tie-break lowest index
//     (matches jax.lax.top_k stability; same rule as round-1 pass)
//   - 128-word LDS bitmask -> masked float4 write-back
// No histograms, no big LDS arrays, no bank conflicts.
// ---------------------------------------------------------------------------
#define POOL 256

__global__ __launch_bounds__(256) void topk_kernel(float* __restrict__ y,
                                                   int* __restrict__ cidx,
                                                   float* __restrict__ cval) {
    const int row = blockIdx.x;                 // row = b*L + l
    float* yr = y + (size_t)row * N_;
    const int tid  = threadIdx.x;
    const int wave = tid >> 6, lane = tid & 63;

    __shared__ unsigned maskbits[N_ / 32];      // 128 u32
    __shared__ float red_f[4];
    __shared__ int   red_i[4];
    __shared__ float bc_f;
    __shared__ int   bc_i;
    __shared__ float pabs[POOL];
    __shared__ float pval[POOL];
    __shared__ int   pidx[POOL];
    __shared__ int   pcnt;

    if (tid < N_ / 32) maskbits[tid] = 0u;
    if (tid == 0) pcnt = 0;

    // load 16 values as 4 float4 (element index of v[4*i+e] = 4*(tid + i*256) + e)
    float4 q[4];
    #pragma unroll
    for (int i = 0; i < 4; ++i)
        q[i] = reinterpret_cast<const float4*>(yr)[tid + i * 256];
    float v[16], a[16];
    #pragma unroll
    for (int i = 0; i < 4; ++i) {
        v[4*i+0] = q[i].x; v[4*i+1] = q[i].y; v[4*i+2] = q[i].z; v[4*i+3] = q[i].w;
    }
    #pragma unroll
    for (int i = 0; i < 16; ++i) a[i] = fabsf(v[i]);

    // block max
    float mx = 0.0f;
    #pragma unroll
    for (int i = 0; i < 16; ++i) mx = fmaxf(mx, a[i]);
    #pragma unroll
    for (int o = 32; o > 0; o >>= 1) mx = fmaxf(mx, __shfl_xor(mx, o, 64));
    if (lane == 0) red_f[wave] = mx;
    __syncthreads();
    if (tid == 0) bc_f = fmaxf(fmaxf(red_f[0], red_f[1]), fmaxf(red_f[2], red_f[3]));
    __syncthreads();
    mx = bc_f;

    // bisect threshold: invariant count(a >= lo) >= S_; shrink until <= POOL
    float lo = 0.0f, hi = mx;
    int cl = N_;
    for (int it = 0; it < 26 && cl > POOL; ++it) {
        float t = 0.5f * (lo + hi);
        int c = 0;
        #pragma unroll
        for (int i = 0; i < 16; ++i) c += (a[i] >= t) ? 1 : 0;
        #pragma unroll
        for (int o = 32; o > 0; o >>= 1) c += __shfl_xor(c, o, 64);
        if (lane == 0) red_i[wave] = c;
        __syncthreads();
        if (tid == 0) bc_i = red_i[0] + red_i[1] + red_i[2] + red_i[3];
        __syncthreads();
        c = bc_i;
        if (c >= S_) { lo = t; cl = c; } else { hi = t; }
    }

    // pool fill (order nondeterministic; final output positions are rank-based
    // and comparisons are commutative -> output deterministic)
    #pragma unroll
    for (int i = 0; i < 16; ++i) {
        if (a[i] >= lo) {
            int p = atomicAdd(&pcnt, 1);
            if (p < POOL) {
                pabs[p] = a[i];
                pval[p] = v[i];
                pidx[p] = 4 * (tid + (i >> 2) * 256) + (i & 3);
            }
        }
    }
    __syncthreads();
    int c = pcnt < POOL ? pcnt : POOL;

    // exact rank with lowest-index tie-break; winners write compact lists + bitmask
    for (int e = tid; e < c; e += 256) {
        float ak = pabs[e]; int ai = pidx[e];
        int rank = 0;
        for (int j = 0; j < c; ++j) {
            float bk = pabs[j];
            rank += ((bk > ak) || (bk == ak && pidx[j] < ai)) ? 1 : 0;
        }
        if (rank < S_) {
            cidx[(size_t)row * S_ + rank] = ai;
            cval[(size_t)row * S_ + rank] = pval[e];
            atomicOr(&maskbits[ai >> 5], 1u << (ai & 31));
        }
    }
    __syncthreads();

    // masked write-back (float4; 4 consecutive element bits live in one word)
    #pragma unroll
    for (int i = 0; i < 4; ++i) {
        int j = tid + i * 256;                 // float4 index
        unsigned w = maskbits[j >> 3];
        int sh = (4 * j) & 31;
        float4 o = q[i];
        if (!((w >> (sh + 0)) & 1u)) o.x = 0.0f;
        if (!((w >> (sh + 1)) & 1u)) o.y = 0.0f;
        if (!((w >> (sh + 2)) & 1u)) o.z = 0.0f;
        if (!((w >> (sh + 3)) & 1u)) o.w = 0.0f;
        reinterpret_cast<float4*>(yr)[j] = o;
    }
}

// ---------------------------------------------------------------------------
// K3: sparse decoder + per-row squared-residual partial
// ---------------------------------------------------------------------------
__global__ __launch_bounds__(128) void decoder_kernel(const float* __restrict__ WdT,
                                                      const int* __restrict__ cidx,
                                                      const float* __restrict__ cval,
                                                      const float* __restrict__ kin,
                                                      float* __restrict__ khat,
                                                      float* __restrict__ partial) {
    int row = blockIdx.x;
    int l = row & (L_ - 1);
    int m = threadIdx.x;
    __shared__ int   sidx[S_];
    __shared__ float sval[S_];
    __shared__ float red[128];
    if (m < S_) { sidx[m] = cidx[(size_t)row * S_ + m]; sval[m] = cval[(size_t)row * S_ + m]; }
    __syncthreads();
    const float* wt = WdT + (size_t)l * N_ * M_;
    float acc = 0.0f;
    #pragma unroll
    for (int j = 0; j < S_; ++j)
        acc = fmaf(sval[j], wt[(size_t)sidx[j] * M_ + m], acc);
    khat[(size_t)row * M_ + m] = acc;
    float r = acc - kin[(size_t)row * M_ + m];
    red[m] = r * r;
    __syncthreads();
    for (int off = 64; off > 0; off >>= 1) {
        if (m < off) red[m] += red[m + off];
        __syncthreads();
    }
    if (m == 0) partial[row] = red[0];
}

// ---------------------------------------------------------------------------
// K4: deterministic reduction of 32768 partials -> loss
// ---------------------------------------------------------------------------
__global__ __launch_bounds__(256) void reduce_loss(const float* __restrict__ partial,
                                                   float* __restrict__ out_loss) {
    __shared__ float red[256];
    int tid = threadIdx.x;
    float s = 0.0f;
    for (int i = tid; i < ROWS; i += 256) s += partial[i];
    red[tid] = s;
    __syncthreads();
    for (int off = 128; off > 0; off >>= 1) {
        if (tid < off) red[tid] += red[tid + off];
        __syncthreads();
    }
    if (tid == 0) out_loss[0] = red[0] / (float)((size_t)B_ * L_ * M_);
}

// ---------------------------------------------------------------------------
extern "C" void kernel_launch(void* const* d_in, const int* in_sizes, int n_in,
                              void* d_out, int out_size, void* d_ws, size_t ws_size,
                              hipStream_t stream) {
    const float* kin = (const float*)d_in[0];   // [B][L][M]
    const float* We  = (const float*)d_in[1];   // [L][N][M]
    // d_in[2] = b_e (unused by reference encode())
    const float* Wd  = (const float*)d_in[3];   // [L][M][N]
    const float* bd  = (const float*)d_in[4];   // [L][M]
    // d_in[5] = s (==32, hardcoded)

    float* out   = (float*)d_out;
    float* loss  = out;                                   // [1]
    float* khat  = out + 1;                               // [B*L*M]
    float* y_out = out + 1 + (size_t)B_ * L_ * M_;        // [B*L*N]

    float* ws      = (float*)d_ws;
    float* WdT     = ws;                                  // L*N*M floats (64 MiB)
    int*   cidx    = (int*)(ws + (size_t)L_ * N_ * M_);   // ROWS*S
    float* cval    = (float*)(cidx + (size_t)ROWS * S_);  // ROWS*S
    float* partial = cval + (size_t)ROWS * S_;            // ROWS

    transpose_wd<<<dim3(N_ / 32, M_ / 32, L_), 256, 0, stream>>>(Wd, WdT);
    encoder_gemm<<<dim3(N_ / BN, B_ / BM, L_), 256, 0, stream>>>(kin, We, bd, y_out);
    topk_kernel<<<ROWS, 256, 0, stream>>>(y_out, cidx, cval);
    decoder_kernel<<<ROWS, 128, 0, stream>>>(WdT, cidx, cval, kin, khat, partial);
    reduce_loss<<<1, 256, 0, stream>>>(partial, loss);
}

// Round 3
// 874.802 us; speedup vs baseline: 2.3226x; 1.2232x over previous
//
#include <hip/hip_runtime.h>
#include <hip/hip_bf16.h>

// Problem constants (fixed by the reference)
#define B_ 1024
#define L_ 32
#define M_ 128
#define N_ 4096
#define S_ 32
#define ROWS (B_ * L_)          // 32768 rows of length N_

// ---------------------------------------------------------------------------
// K0: transpose W_d [L][M][N] -> W_dT [L][N][M] (for coalesced decoder gathers)
// ---------------------------------------------------------------------------
__global__ __launch_bounds__(256) void transpose_wd(const float* __restrict__ Wd,
                                                    float* __restrict__ WdT) {
    __shared__ float t[32][33];
    int l = blockIdx.z;
    int n0 = blockIdx.x * 32, m0 = blockIdx.y * 32;
    int tx = threadIdx.x & 31, ty = threadIdx.x >> 5;   // 8 rows of 32
    const float* src = Wd + (size_t)l * M_ * N_;
    for (int i = ty; i < 32; i += 8)
        t[i][tx] = src[(size_t)(m0 + i) * N_ + n0 + tx];
    __syncthreads();
    float* dst = WdT + (size_t)l * N_ * M_;
    for (int i = ty; i < 32; i += 8)
        dst[(size_t)(n0 + i) * M_ + m0 + tx] = t[tx][i];
}

// ---------------------------------------------------------------------------
// K0b: c[l][n] = dot(b_d[l], W_e[l][n])   (hoists the k-b_d subtraction out of
// the GEMM so staging can use global_load_lds; acc is initialized to -c)
// 16 n per block, 16 threads per n (coalesced 512B row reads), shfl reduce.
// ---------------------------------------------------------------------------
__global__ __launch_bounds__(256) void bias_dot(const float* __restrict__ We,
                                                const float* __restrict__ bd,
                                                float* __restrict__ c) {
    int l = blockIdx.y;
    int tid = threadIdx.x;
    int nl = tid >> 4, l16 = tid & 15;
    int n = blockIdx.x * 16 + nl;
    const float* w = We + ((size_t)l * N_ + n) * M_ + l16 * 8;
    const float* b = bd + l * M_ + l16 * 8;
    float4 w0 = *(const float4*)(w), w1 = *(const float4*)(w + 4);
    float4 b0 = *(const float4*)(b), b1 = *(const float4*)(b + 4);
    float s = w0.x*b0.x + w0.y*b0.y + w0.z*b0.z + w0.w*b0.w
            + w1.x*b1.x + w1.y*b1.y + w1.z*b1.z + w1.w*b1.w;
    #pragma unroll
    for (int o = 8; o > 0; o >>= 1) s += __shfl_xor(s, o, 64);
    if (l16 == 0) c[(size_t)l * N_ + n] = s;
}

// ---------------------------------------------------------------------------
// K1: encoder GEMM (f32), 128x128 tile, BK=32, 8x8 microtile.
//  - staging: global_load_lds dwordx4, linear LDS dest, inverse-swizzled
//    global source (swizzle only permutes float4s within one 128B row)
//  - LDS layout: [row][32] f32, float4 slot s stores logical k4 = s ^ ((row>>3)&7)
//    -> B-fragment reads 2-way aliased (free), A-fragment reads broadcast.
// ---------------------------------------------------------------------------
__global__ __launch_bounds__(256, 3) void encoder_gemm(const float* __restrict__ kin,
                                                       const float* __restrict__ We,
                                                       const float* __restrict__ cvec,
                                                       float* __restrict__ y_out) {
    const int l   = blockIdx.z;
    const int bn0 = blockIdx.x * 128;
    const int bm0 = blockIdx.y * 128;
    __shared__ float As[128 * 32];
    __shared__ float Bs[128 * 32];
    const int tid = threadIdx.x;
    const int tx = tid & 15, ty = tid >> 4;
    const float* wel = We + (size_t)l * N_ * M_;

    // stage one K-slice (k0) of A and B via global_load_lds (16B/lane)
    auto stage = [&](int k0) {
        #pragma unroll
        for (int i = 0; i < 4; ++i) {
            int p   = i * 256 + tid;          // float4 index 0..1023 (linear LDS)
            int row = p >> 3;                 // tile-local row
            int sw  = (row >> 3) & 7;         // wave-constant within each call
            int k4  = (p & 7) ^ sw;           // inverse swizzle on the SOURCE
            const float* ga = kin + ((size_t)((bm0 + row) * L_ + l)) * M_ + k0 + (k4 << 2);
            unsigned dstf = (unsigned)((i * 256 + (tid & ~63)) << 2);  // wave-uniform
            __builtin_amdgcn_global_load_lds(
                (const __attribute__((address_space(1))) void*)ga,
                (__attribute__((address_space(3))) void*)(As + dstf), 16, 0, 0);
        }
        #pragma unroll
        for (int i = 0; i < 4; ++i) {
            int p   = i * 256 + tid;
            int row = p >> 3;
            int sw  = (row >> 3) & 7;
            int k4  = (p & 7) ^ sw;
            const float* gb = wel + (size_t)(bn0 + row) * M_ + k0 + (k4 << 2);
            unsigned dstf = (unsigned)((i * 256 + (tid & ~63)) << 2);
            __builtin_amdgcn_global_load_lds(
                (const __attribute__((address_space(1))) void*)gb,
                (__attribute__((address_space(3))) void*)(Bs + dstf), 16, 0, 0);
        }
    };

    // acc init = -c[l][bn0 + tx*8 + j]
    float acc[8][8];
    {
        const float* cl = cvec + (size_t)l * N_ + bn0 + tx * 8;
        float4 c0 = *(const float4*)(cl);
        float4 c1 = *(const float4*)(cl + 4);
        float cj[8] = {c0.x, c0.y, c0.z, c0.w, c1.x, c1.y, c1.z, c1.w};
        #pragma unroll
        for (int i = 0; i < 8; ++i)
            #pragma unroll
            for (int j = 0; j < 8; ++j) acc[i][j] = -cj[j];
    }

    const int sA = ty & 7;
    const int sB = tx & 7;

    stage(0);
    __syncthreads();   // drains vmcnt -> staged data visible

    #pragma unroll
    for (int t = 0; t < 4; ++t) {
        // compute on slice t
        #pragma unroll
        for (int s = 0; s < 8; ++s) {        // logical k4, ascending (matches ref order)
            const int offA = (s ^ sA) << 2;
            const int offB = (s ^ sB) << 2;
            float4 av[8], bv[8];
            #pragma unroll
            for (int i = 0; i < 8; ++i)
                av[i] = *reinterpret_cast<const float4*>(&As[(ty * 8 + i) * 32 + offA]);
            #pragma unroll
            for (int j = 0; j < 8; ++j)
                bv[j] = *reinterpret_cast<const float4*>(&Bs[(tx * 8 + j) * 32 + offB]);
            #pragma unroll
            for (int i = 0; i < 8; ++i)
                #pragma unroll
                for (int j = 0; j < 8; ++j) {
                    acc[i][j] = fmaf(av[i].x, bv[j].x, acc[i][j]);
                    acc[i][j] = fmaf(av[i].y, bv[j].y, acc[i][j]);
                    acc[i][j] = fmaf(av[i].z, bv[j].z, acc[i][j]);
                    acc[i][j] = fmaf(av[i].w, bv[j].w, acc[i][j]);
                }
        }
        if (t < 3) {
            __syncthreads();                 // everyone done reading slice t
            stage((t + 1) * 32);
            __syncthreads();                 // vmcnt drained: slice t+1 ready
        }
    }

    // epilogue: write y rows (two float4 stores per row; y base is 4B-aligned
    // only -- unaligned dwordx4 works on gfx950, verified by round-2 topk)
    #pragma unroll
    for (int i = 0; i < 8; ++i) {
        int b = bm0 + ty * 8 + i;
        float* dst = y_out + ((size_t)(b * L_ + l)) * N_ + bn0 + tx * 8;
        float4 o0 = {acc[i][0], acc[i][1], acc[i][2], acc[i][3]};
        float4 o1 = {acc[i][4], acc[i][5], acc[i][6], acc[i][7]};
        *reinterpret_cast<float4*>(dst)     = o0;
        *reinterpret_cast<float4*>(dst + 4) = o1;
    }
}

// ---------------------------------------------------------------------------
// K2: exact top-32 per row, register-resident (unchanged from round 2)
// ---------------------------------------------------------------------------
#define POOL 256

__global__ __launch_bounds__(256) void topk_kernel(float* __restrict__ y,
                                                   int* __restrict__ cidx,
                                                   float* __restrict__ cval) {
    const int row = blockIdx.x;                 // row = b*L + l
    float* yr = y + (size_t)row * N_;
    const int tid  = threadIdx.x;
    const int wave = tid >> 6, lane = tid & 63;

    __shared__ unsigned maskbits[N_ / 32];      // 128 u32
    __shared__ float red_f[4];
    __shared__ int   red_i[4];
    __shared__ float bc_f;
    __shared__ int   bc_i;
    __shared__ float pabs[POOL];
    __shared__ float pval[POOL];
    __shared__ int   pidx[POOL];
    __shared__ int   pcnt;

    if (tid < N_ / 32) maskbits[tid] = 0u;
    if (tid == 0) pcnt = 0;

    float4 q[4];
    #pragma unroll
    for (int i = 0; i < 4; ++i)
        q[i] = reinterpret_cast<const float4*>(yr)[tid + i * 256];
    float v[16], a[16];
    #pragma unroll
    for (int i = 0; i < 4; ++i) {
        v[4*i+0] = q[i].x; v[4*i+1] = q[i].y; v[4*i+2] = q[i].z; v[4*i+3] = q[i].w;
    }
    #pragma unroll
    for (int i = 0; i < 16; ++i) a[i] = fabsf(v[i]);

    float mx = 0.0f;
    #pragma unroll
    for (int i = 0; i < 16; ++i) mx = fmaxf(mx, a[i]);
    #pragma unroll
    for (int o = 32; o > 0; o >>= 1) mx = fmaxf(mx, __shfl_xor(mx, o, 64));
    if (lane == 0) red_f[wave] = mx;
    __syncthreads();
    if (tid == 0) bc_f = fmaxf(fmaxf(red_f[0], red_f[1]), fmaxf(red_f[2], red_f[3]));
    __syncthreads();
    mx = bc_f;

    float lo = 0.0f, hi = mx;
    int cl = N_;
    for (int it = 0; it < 26 && cl > POOL; ++it) {
        float t = 0.5f * (lo + hi);
        int c = 0;
        #pragma unroll
        for (int i = 0; i < 16; ++i) c += (a[i] >= t) ? 1 : 0;
        #pragma unroll
        for (int o = 32; o > 0; o >>= 1) c += __shfl_xor(c, o, 64);
        if (lane == 0) red_i[wave] = c;
        __syncthreads();
        if (tid == 0) bc_i = red_i[0] + red_i[1] + red_i[2] + red_i[3];
        __syncthreads();
        c = bc_i;
        if (c >= S_) { lo = t; cl = c; } else { hi = t; }
    }

    #pragma unroll
    for (int i = 0; i < 16; ++i) {
        if (a[i] >= lo) {
            int p = atomicAdd(&pcnt, 1);
            if (p < POOL) {
                pabs[p] = a[i];
                pval[p] = v[i];
                pidx[p] = 4 * (tid + (i >> 2) * 256) + (i & 3);
            }
        }
    }
    __syncthreads();
    int c = pcnt < POOL ? pcnt : POOL;

    for (int e = tid; e < c; e += 256) {
        float ak = pabs[e]; int ai = pidx[e];
        int rank = 0;
        for (int j = 0; j < c; ++j) {
            float bk = pabs[j];
            rank += ((bk > ak) || (bk == ak && pidx[j] < ai)) ? 1 : 0;
        }
        if (rank < S_) {
            cidx[(size_t)row * S_ + rank] = ai;
            cval[(size_t)row * S_ + rank] = pval[e];
            atomicOr(&maskbits[ai >> 5], 1u << (ai & 31));
        }
    }
    __syncthreads();

    #pragma unroll
    for (int i = 0; i < 4; ++i) {
        int j = tid + i * 256;
        unsigned w = maskbits[j >> 3];
        int sh = (4 * j) & 31;
        float4 o = q[i];
        if (!((w >> (sh + 0)) & 1u)) o.x = 0.0f;
        if (!((w >> (sh + 1)) & 1u)) o.y = 0.0f;
        if (!((w >> (sh + 2)) & 1u)) o.z = 0.0f;
        if (!((w >> (sh + 3)) & 1u)) o.w = 0.0f;
        reinterpret_cast<float4*>(yr)[j] = o;
    }
}

// ---------------------------------------------------------------------------
// K3: sparse decoder + per-row squared-residual partial
// ---------------------------------------------------------------------------
__global__ __launch_bounds__(128) void decoder_kernel(const float* __restrict__ WdT,
                                                      const int* __restrict__ cidx,
                                                      const float* __restrict__ cval,
                                                      const float* __restrict__ kin,
                                                      float* __restrict__ khat,
                                                      float* __restrict__ partial) {
    int row = blockIdx.x;
    int l = row & (L_ - 1);
    int m = threadIdx.x;
    __shared__ int   sidx[S_];
    __shared__ float sval[S_];
    __shared__ float red[128];
    if (m < S_) { sidx[m] = cidx[(size_t)row * S_ + m]; sval[m] = cval[(size_t)row * S_ + m]; }
    __syncthreads();
    const float* wt = WdT + (size_t)l * N_ * M_;
    float acc = 0.0f;
    #pragma unroll
    for (int j = 0; j < S_; ++j)
        acc = fmaf(sval[j], wt[(size_t)sidx[j] * M_ + m], acc);
    khat[(size_t)row * M_ + m] = acc;
    float r = acc - kin[(size_t)row * M_ + m];
    red[m] = r * r;
    __syncthreads();
    for (int off = 64; off > 0; off >>= 1) {
        if (m < off) red[m] += red[m + off];
        __syncthreads();
    }
    if (m == 0) partial[row] = red[0];
}

// ---------------------------------------------------------------------------
// K4: deterministic reduction of 32768 partials -> loss
// ---------------------------------------------------------------------------
__global__ __launch_bounds__(256) void reduce_loss(const float* __restrict__ partial,
                                                   float* __restrict__ out_loss) {
    __shared__ float red[256];
    int tid = threadIdx.x;
    float s = 0.0f;
    for (int i = tid; i < ROWS; i += 256) s += partial[i];
    red[tid] = s;
    __syncthreads();
    for (int off = 128; off > 0; off >>= 1) {
        if (tid < off) red[tid] += red[tid + off];
        __syncthreads();
    }
    if (tid == 0) out_loss[0] = red[0] / (float)((size_t)B_ * L_ * M_);
}

// ---------------------------------------------------------------------------
extern "C" void kernel_launch(void* const* d_in, const int* in_sizes, int n_in,
                              void* d_out, int out_size, void* d_ws, size_t ws_size,
                              hipStream_t stream) {
    const float* kin = (const float*)d_in[0];   // [B][L][M]
    const float* We  = (const float*)d_in[1];   // [L][N][M]
    // d_in[2] = b_e (unused by reference encode())
    const float* Wd  = (const float*)d_in[3];   // [L][M][N]
    const float* bd  = (const float*)d_in[4];   // [L][M]
    // d_in[5] = s (==32, hardcoded)

    float* out   = (float*)d_out;
    float* loss  = out;                                   // [1]
    float* khat  = out + 1;                               // [B*L*M]
    float* y_out = out + 1 + (size_t)B_ * L_ * M_;        // [B*L*N]

    float* ws      = (float*)d_ws;
    float* WdT     = ws;                                  // L*N*M floats (64 MiB)
    int*   cidx    = (int*)(ws + (size_t)L_ * N_ * M_);   // ROWS*S
    float* cval    = (float*)(cidx + (size_t)ROWS * S_);  // ROWS*S
    float* partial = cval + (size_t)ROWS * S_;            // ROWS
    // c aliases cidx: c is only live during encoder_gemm; cidx is written by
    // topk strictly after encoder_gemm completes.
    float* cvec    = (float*)cidx;                        // L*N floats (512 KB)

    bias_dot<<<dim3(N_ / 16, L_), 256, 0, stream>>>(We, bd, cvec);
    transpose_wd<<<dim3(N_ / 32, M_ / 32, L_), 256, 0, stream>>>(Wd, WdT);
    encoder_gemm<<<dim3(N_ / 128, B_ / 128, L_), 256, 0, stream>>>(kin, We, cvec, y_out);
    topk_kernel<<<ROWS, 256, 0, stream>>>(y_out, cidx, cval);
    decoder_kernel<<<ROWS, 128, 0, stream>>>(WdT, cidx, cval, kin, khat, partial);
    reduce_loss<<<1, 256, 0, stream>>>(partial, loss);
}

// Round 4
// 804.802 us; speedup vs baseline: 2.5246x; 1.0870x over previous
//
#include <hip/hip_runtime.h>
#include <hip/hip_bf16.h>

// Problem constants (fixed by the reference)
#define B_ 1024
#define L_ 32
#define M_ 128
#define N_ 4096
#define S_ 32
#define ROWS (B_ * L_)          // 32768 rows of length N_

typedef __attribute__((ext_vector_type(8))) short    short8_t;   // 8 bf16 (4 VGPR)
typedef __attribute__((ext_vector_type(8))) unsigned short ushort8_t;
typedef __attribute__((ext_vector_type(4))) float    f32x4;

__device__ __forceinline__ unsigned short f2bf(float x) {  // RNE bf16
    unsigned u = __float_as_uint(x);
    unsigned r = (u + 0x7FFFu + ((u >> 16) & 1u)) >> 16;
    return (unsigned short)r;
}
__device__ __forceinline__ float bf2f(unsigned short h) {
    return __uint_as_float((unsigned)h << 16);
}

// ---------------------------------------------------------------------------
// K0: transpose W_d [L][M][N] -> W_dT [L][N][M] (runs AFTER encoder; WdT
// aliases the Wbf region)
// ---------------------------------------------------------------------------
__global__ __launch_bounds__(256) void transpose_wd(const float* __restrict__ Wd,
                                                    float* __restrict__ WdT) {
    __shared__ float t[32][33];
    int l = blockIdx.z;
    int n0 = blockIdx.x * 32, m0 = blockIdx.y * 32;
    int tx = threadIdx.x & 31, ty = threadIdx.x >> 5;
    const float* src = Wd + (size_t)l * M_ * N_;
    for (int i = ty; i < 32; i += 8)
        t[i][tx] = src[(size_t)(m0 + i) * N_ + n0 + tx];
    __syncthreads();
    float* dst = WdT + (size_t)l * N_ * M_;
    for (int i = ty; i < 32; i += 8)
        dst[(size_t)(n0 + i) * M_ + m0 + tx] = t[tx][i];
}

// ---------------------------------------------------------------------------
// K0b: c[l][n] = dot(b_d[l], W_e[l][n])
// ---------------------------------------------------------------------------
__global__ __launch_bounds__(256) void bias_dot(const float* __restrict__ We,
                                                const float* __restrict__ bd,
                                                float* __restrict__ c) {
    int l = blockIdx.y;
    int tid = threadIdx.x;
    int nl = tid >> 4, l16 = tid & 15;
    int n = blockIdx.x * 16 + nl;
    const float* w = We + ((size_t)l * N_ + n) * M_ + l16 * 8;
    const float* b = bd + l * M_ + l16 * 8;
    float4 w0 = *(const float4*)(w), w1 = *(const float4*)(w + 4);
    float4 b0 = *(const float4*)(b), b1 = *(const float4*)(b + 4);
    float s = w0.x*b0.x + w0.y*b0.y + w0.z*b0.z + w0.w*b0.w
            + w1.x*b1.x + w1.y*b1.y + w1.z*b1.z + w1.w*b1.w;
    #pragma unroll
    for (int o = 8; o > 0; o >>= 1) s += __shfl_xor(s, o, 64);
    if (l16 == 0) c[(size_t)l * N_ + n] = s;
}

// ---------------------------------------------------------------------------
// P1: split kin -> Abf [l][b][256] bf16: seg0 = a1 = bf16(k), seg1 = a2 = bf16(k-a1)
// ---------------------------------------------------------------------------
__global__ __launch_bounds__(256) void prep_a(const float* __restrict__ kin,
                                              unsigned short* __restrict__ Abf) {
    int g = blockIdx.x * 256 + threadIdx.x;       // over B*L*M
    int b = g >> 12, l = (g >> 7) & 31, m = g & 127;
    float x = kin[g];
    unsigned short a1 = f2bf(x);
    unsigned short a2 = f2bf(x - bf2f(a1));
    size_t base = ((size_t)l * B_ + b) * 256;
    Abf[base + m]       = a1;
    Abf[base + 128 + m] = a2;
}

// P2: split We -> Wbf [l][n][256] bf16: seg0 = w1, seg1 = w2
__global__ __launch_bounds__(256) void prep_w(const float* __restrict__ We,
                                              unsigned short* __restrict__ Wbf) {
    int g = blockIdx.x * 256 + threadIdx.x;       // over L*N*M
    int l = g >> 19, n = (g >> 7) & 4095, m = g & 127;
    float x = We[g];
    unsigned short w1 = f2bf(x);
    unsigned short w2 = f2bf(x - bf2f(w1));
    size_t base = ((size_t)l * N_ + n) * 256;
    Wbf[base + m]       = w1;
    Wbf[base + 128 + m] = w2;
}

// ---------------------------------------------------------------------------
// K1: encoder approx GEMM via MFMA bf16, 3-term split:
//   y ~= a1*w1 + a1*w2 + a2*w1 (effective K = 384, 12 BK=32 steps)
// m97-style: 128x128 tile, 4 waves (2x2 of 64x64), 16x16x32 MFMA,
// global_load_lds(16B) staging w/ inverse-chunk-swizzled source,
// chunk-XOR swizzle in LDS for conflict-light ds_read_b128.
// Output: bf16 y_approx stored in the low half of each row's 16KB slot.
// ---------------------------------------------------------------------------
__device__ __forceinline__ int swz(int row) { return (row & 3) ^ ((row >> 2) & 3); }

__global__ __launch_bounds__(256) void encoder_mfma(const unsigned short* __restrict__ Abf,
                                                    const unsigned short* __restrict__ Wbf,
                                                    const float* __restrict__ cvec,
                                                    unsigned short* __restrict__ y16) {
    const int l   = blockIdx.z;
    const int bn0 = blockIdx.x * 128;
    const int bm0 = blockIdx.y * 128;
    __shared__ __align__(16) unsigned short As[128 * 32];
    __shared__ __align__(16) unsigned short Bs[128 * 32];
    const int tid  = threadIdx.x;
    const int lane = tid & 63, wave = tid >> 6;
    const int wr = wave >> 1, wc = wave & 1;

    const unsigned short* Ab = Abf + ((size_t)l * B_ + bm0) * 256;
    const unsigned short* Wb = Wbf + ((size_t)l * N_ + bn0) * 256;

    auto stage = [&](int kA0, int kW0) {
        #pragma unroll
        for (int i = 0; i < 2; ++i) {
            int p   = i * 256 + tid;
            int row = p >> 2;
            int lc  = (p & 3) ^ swz(row);                 // logical chunk for this slot
            const unsigned short* g = Ab + (size_t)row * 256 + kA0 + lc * 8;
            unsigned dst = (unsigned)((i * 256 + (tid & ~63)) * 16);
            __builtin_amdgcn_global_load_lds(
                (const __attribute__((address_space(1))) void*)g,
                (__attribute__((address_space(3))) void*)((char*)As + dst), 16, 0, 0);
        }
        #pragma unroll
        for (int i = 0; i < 2; ++i) {
            int p   = i * 256 + tid;
            int row = p >> 2;
            int lc  = (p & 3) ^ swz(row);
            const unsigned short* g = Wb + (size_t)row * 256 + kW0 + lc * 8;
            unsigned dst = (unsigned)((i * 256 + (tid & ~63)) * 16);
            __builtin_amdgcn_global_load_lds(
                (const __attribute__((address_space(1))) void*)g,
                (__attribute__((address_space(3))) void*)((char*)Bs + dst), 16, 0, 0);
        }
    };

    f32x4 acc[4][4];
    #pragma unroll
    for (int i = 0; i < 4; ++i)
        #pragma unroll
        for (int j = 0; j < 4; ++j) acc[i][j] = (f32x4){0.f, 0.f, 0.f, 0.f};

    // K-step t in [0,12): seg = t>>2. (A-seg, W-seg) = (0,0), (0,1), (1,0)
    stage(0, 0);
    __syncthreads();

    #pragma unroll
    for (int t = 0; t < 12; ++t) {
        short8_t aF[4], bF[4];
        const int kg = lane >> 4;
        #pragma unroll
        for (int mt = 0; mt < 4; ++mt) {
            int row = wr * 64 + mt * 16 + (lane & 15);
            int pc  = kg ^ swz(row);
            aF[mt] = *reinterpret_cast<const short8_t*>(As + row * 32 + pc * 8);
        }
        #pragma unroll
        for (int nt = 0; nt < 4; ++nt) {
            int row = wc * 64 + nt * 16 + (lane & 15);
            int pc  = kg ^ swz(row);
            bF[nt] = *reinterpret_cast<const short8_t*>(Bs + row * 32 + pc * 8);
        }
        #pragma unroll
        for (int mt = 0; mt < 4; ++mt)
            #pragma unroll
            for (int nt = 0; nt < 4; ++nt)
                acc[mt][nt] = __builtin_amdgcn_mfma_f32_16x16x32_bf16(
                    aF[mt], bF[nt], acc[mt][nt], 0, 0, 0);

        if (t < 11) {
            int tn  = t + 1;
            int seg = tn >> 2, r = (tn & 3) * 32;
            int ka  = (seg == 2) ? 128 + r : r;
            int kw  = (seg == 1) ? 128 + r : r;
            __syncthreads();          // everyone done reading tile t
            stage(ka, kw);
            __syncthreads();          // glds drained: tile t+1 ready
        }
    }

    // epilogue: y16[row_slot][n] = bf16(acc - c), C/D map col=lane&15, row=(lane>>4)*4+j
    #pragma unroll
    for (int nt = 0; nt < 4; ++nt) {
        int n = bn0 + wc * 64 + nt * 16 + (lane & 15);
        float cj = cvec[(size_t)l * N_ + n];
        #pragma unroll
        for (int mt = 0; mt < 4; ++mt) {
            #pragma unroll
            for (int j = 0; j < 4; ++j) {
                int b = bm0 + wr * 64 + mt * 16 + (lane >> 4) * 4 + j;
                y16[((size_t)(b * L_ + l)) * 8192 + n] = f2bf(acc[mt][nt][j] - cj);
            }
        }
    }
}

// ---------------------------------------------------------------------------
// K2: exact top-32. Bisect on |y_approx| (bf16), pool candidates >= lo-MARGIN
// (provably contains exact top-32), recompute pool EXACTLY (ascending-k f32,
// matches reference accumulation order), rank exactly, write zeros + exact.
// In-place: approx bf16 lives in low 8KB of each row's 16KB slot.
// ---------------------------------------------------------------------------
#define POOL 320
#define MARGIN 8e-4f

__global__ __launch_bounds__(256) void topk_kernel(float* __restrict__ y,
                                                   const float* __restrict__ We,
                                                   const float* __restrict__ kin,
                                                   const float* __restrict__ cvec,
                                                   int* __restrict__ cidx,
                                                   float* __restrict__ cval) {
    const int row = blockIdx.x;                 // row = b*L + l
    const int b = row >> 5, l = row & 31;
    const unsigned short* ya = (const unsigned short*)y + (size_t)row * 8192;
    float* yo = y + (size_t)row * N_;
    const int tid  = threadIdx.x;
    const int wave = tid >> 6, lane = tid & 63;

    __shared__ float kinL[M_];
    __shared__ float red_f[4];
    __shared__ int   red_i[4];
    __shared__ float bc_f;
    __shared__ int   bc_i;
    __shared__ int   pidxS[POOL];
    __shared__ float pexS[POOL];
    __shared__ int   pcnt;

    if (tid < M_) kinL[tid] = kin[((size_t)b * L_ + l) * M_ + tid];
    if (tid == 0) pcnt = 0;

    // load 16 approx values (two 16B loads), thread-local slots
    ushort8_t u0 = *reinterpret_cast<const ushort8_t*>(ya + tid * 8);
    ushort8_t u1 = *reinterpret_cast<const ushort8_t*>(ya + 2048 + tid * 8);
    float a[16];
    #pragma unroll
    for (int i = 0; i < 8; ++i) {
        a[i]     = fabsf(bf2f(u0[i]));
        a[8 + i] = fabsf(bf2f(u1[i]));
    }

    // block max
    float mx = 0.0f;
    #pragma unroll
    for (int i = 0; i < 16; ++i) mx = fmaxf(mx, a[i]);
    #pragma unroll
    for (int o = 32; o > 0; o >>= 1) mx = fmaxf(mx, __shfl_xor(mx, o, 64));
    if (lane == 0) red_f[wave] = mx;
    __syncthreads();
    if (tid == 0) bc_f = fmaxf(fmaxf(red_f[0], red_f[1]), fmaxf(red_f[2], red_f[3]));
    __syncthreads();
    mx = bc_f;

    // bisect: invariant count(a >= lo) >= 32; tighten until count <= 48
    float lo = 0.0f, hi = mx;
    int cl = N_;
    for (int it = 0; it < 30 && cl > 48; ++it) {
        float t = 0.5f * (lo + hi);
        int c = 0;
        #pragma unroll
        for (int i = 0; i < 16; ++i) c += (a[i] >= t) ? 1 : 0;
        #pragma unroll
        for (int o = 32; o > 0; o >>= 1) c += __shfl_xor(c, o, 64);
        if (lane == 0) red_i[wave] = c;
        __syncthreads();
        if (tid == 0) bc_i = red_i[0] + red_i[1] + red_i[2] + red_i[3];
        __syncthreads();
        c = bc_i;
        if (c >= S_) { lo = t; cl = c; } else { hi = t; }
    }

    // pool: everything with approx >= lo - MARGIN  (covers exact top-32)
    const float th = lo - MARGIN;
    #pragma unroll
    for (int i = 0; i < 16; ++i) {
        if (a[i] >= th) {
            int p = atomicAdd(&pcnt, 1);
            if (p < POOL) pidxS[p] = (i < 8) ? (tid * 8 + i) : (2048 + tid * 8 + i - 8);
        }
    }
    __syncthreads();
    int c = pcnt < POOL ? pcnt : POOL;

    // exact recompute: y[n] = -c[l][n] + sum_m We[l][n][m]*kin[b][l][m], ascending m
    for (int e = tid; e < c; e += 256) {
        int n = pidxS[e];
        const float* w = We + ((size_t)l * N_ + n) * M_;
        float acc = -cvec[(size_t)l * N_ + n];
        #pragma unroll 8
        for (int m = 0; m < M_; ++m) acc = fmaf(w[m], kinL[m], acc);
        pexS[e] = acc;
    }

    // zero the full row (thread-local slots exactly cover own approx bytes)
    float4 z = {0.f, 0.f, 0.f, 0.f};
    #pragma unroll
    for (int i = 0; i < 4; ++i)
        *reinterpret_cast<float4*>(yo + 4 * (tid + i * 256)) = z;
    __syncthreads();

    // exact rank (lowest-index tie-break), emit winners
    for (int e = tid; e < c; e += 256) {
        float ae = fabsf(pexS[e]);
        int   ne = pidxS[e];
        int rank = 0;
        for (int j = 0; j < c; ++j) {
            float aj = fabsf(pexS[j]);
            rank += ((aj > ae) || (aj == ae && pidxS[j] < ne)) ? 1 : 0;
        }
        if (rank < S_) {
            cidx[(size_t)row * S_ + rank] = ne;
            cval[(size_t)row * S_ + rank] = pexS[e];
            yo[ne] = pexS[e];
        }
    }
}

// ---------------------------------------------------------------------------
// K3: sparse decoder + per-row squared-residual partial
// ---------------------------------------------------------------------------
__global__ __launch_bounds__(128) void decoder_kernel(const float* __restrict__ WdT,
                                                      const int* __restrict__ cidx,
                                                      const float* __restrict__ cval,
                                                      const float* __restrict__ kin,
                                                      float* __restrict__ khat,
                                                      float* __restrict__ partial) {
    int row = blockIdx.x;
    int l = row & (L_ - 1);
    int m = threadIdx.x;
    __shared__ int   sidx[S_];
    __shared__ float sval[S_];
    __shared__ float red[128];
    if (m < S_) { sidx[m] = cidx[(size_t)row * S_ + m]; sval[m] = cval[(size_t)row * S_ + m]; }
    __syncthreads();
    const float* wt = WdT + (size_t)l * N_ * M_;
    float acc = 0.0f;
    #pragma unroll
    for (int j = 0; j < S_; ++j)
        acc = fmaf(sval[j], wt[(size_t)sidx[j] * M_ + m], acc);
    khat[(size_t)row * M_ + m] = acc;
    float r = acc - kin[(size_t)row * M_ + m];
    red[m] = r * r;
    __syncthreads();
    for (int off = 64; off > 0; off >>= 1) {
        if (m < off) red[m] += red[m + off];
        __syncthreads();
    }
    if (m == 0) partial[row] = red[0];
}

// ---------------------------------------------------------------------------
// K4: deterministic reduction of 32768 partials -> loss
// ---------------------------------------------------------------------------
__global__ __launch_bounds__(256) void reduce_loss(const float* __restrict__ partial,
                                                   float* __restrict__ out_loss) {
    __shared__ float red[256];
    int tid = threadIdx.x;
    float s = 0.0f;
    for (int i = tid; i < ROWS; i += 256) s += partial[i];
    red[tid] = s;
    __syncthreads();
    for (int off = 128; off > 0; off >>= 1) {
        if (tid < off) red[tid] += red[tid + off];
        __syncthreads();
    }
    if (tid == 0) out_loss[0] = red[0] / (float)((size_t)B_ * L_ * M_);
}

// ---------------------------------------------------------------------------
extern "C" void kernel_launch(void* const* d_in, const int* in_sizes, int n_in,
                              void* d_out, int out_size, void* d_ws, size_t ws_size,
                              hipStream_t stream) {
    const float* kin = (const float*)d_in[0];   // [B][L][M]
    const float* We  = (const float*)d_in[1];   // [L][N][M]
    // d_in[2] = b_e (unused by reference encode())
    const float* Wd  = (const float*)d_in[3];   // [L][M][N]
    const float* bd  = (const float*)d_in[4];   // [L][M]
    // d_in[5] = s (==32, hardcoded)

    float* out   = (float*)d_out;
    float* loss  = out;                                   // [1]
    float* khat  = out + 1;                               // [B*L*M]
    float* y_out = out + 1 + (size_t)B_ * L_ * M_;        // [B*L*N]

    // workspace layout (region0 is shared: Wbf during encode, WdT after)
    char* ws = (char*)d_ws;
    unsigned short* Wbf = (unsigned short*)ws;                   // 64 MiB
    float*          WdT = (float*)ws;                            // 64 MiB (aliases Wbf)
    unsigned short* Abf = (unsigned short*)(ws + (64u << 20));   // 16 MiB
    float* cvec    = (float*)(ws + (80u << 20));                 // 512 KiB
    int*   cidx    = (int*)  (ws + (80u << 20) + (512u << 10));  // 4 MiB
    float* cval    = (float*)(ws + (84u << 20) + (512u << 10));  // 4 MiB
    float* partial = (float*)(ws + (88u << 20) + (512u << 10));  // 128 KiB

    bias_dot<<<dim3(N_ / 16, L_), 256, 0, stream>>>(We, bd, cvec);
    prep_a<<<(B_ * L_ * M_) / 256, 256, 0, stream>>>(kin, Abf);
    prep_w<<<(L_ * N_ * M_) / 256, 256, 0, stream>>>(We, Wbf);
    encoder_mfma<<<dim3(N_ / 128, B_ / 128, L_), 256, 0, stream>>>(
        Abf, Wbf, cvec, (unsigned short*)y_out);
    // Wbf dead now; transpose overwrites region0 with WdT
    transpose_wd<<<dim3(N_ / 32, M_ / 32, L_), 256, 0, stream>>>(Wd, WdT);
    topk_kernel<<<ROWS, 256, 0, stream>>>(y_out, We, kin, cvec, cidx, cval);
    decoder_kernel<<<ROWS, 128, 0, stream>>>(WdT, cidx, cval, kin, khat, partial);
    reduce_loss<<<1, 256, 0, stream>>>(partial, loss);
}